// Round 16
// baseline (142.288 us; speedup 1.0000x reference)
//
#include <hip/hip_runtime.h>
#include <hip/hip_bf16.h>

typedef short bf16x8 __attribute__((ext_vector_type(8)));
typedef float f32x4 __attribute__((ext_vector_type(4)));

#define LN_EPS 1e-5f
#define SLOPE 0.2f

__device__ __forceinline__ float bf2f(unsigned short s){
  return __uint_as_float(((unsigned)s) << 16);
}
// Native conversion: compiler fuses adjacent pairs to v_cvt_pk_bf16_f32 (m240).
__device__ __forceinline__ unsigned short f2bf(float f){
  __hip_bfloat16 b = __float2bfloat16(f);
  return *reinterpret_cast<unsigned short*>(&b);
}

// Verified W image (rounds 1..15):
// wbf[((s*4+g)*512 + c)*8 + j] = W[k = s*32+g*8+j][c]   (c<256: W_l, else W_r)
__global__ void wconv_kernel(const float* __restrict__ Wl,
                             const float* __restrict__ Wr,
                             unsigned short* __restrict__ wbf){
  int idx = blockIdx.x * 256 + threadIdx.x;   // 0..16383 : (s,g,c)
  int c = idx & 511;
  int gg = (idx >> 9) & 3;
  int s = idx >> 11;
  int k0 = s * 32 + gg * 8;
  const float* src = (c < 256) ? (Wl + c) : (Wr + (c - 256));
  bf16x8 v;
  #pragma unroll
  for (int j = 0; j < 8; ++j) v[j] = (short)f2bf(src[(k0 + j) * 256]);
  *(bf16x8*)&wbf[(size_t)idx * 8] = v;
}

// ============ SPLIT PATH (ws large): kernel A = verified GEMM, g -> ws bf16 ============
// g layout: idx16 = ((blk*4 + w)*2 + m)*8 + c ; gws[idx16*256 + lane*4 .. +3] = acc[m][c][0..3]
__global__ __launch_bounds__(256, 2)
void gemm_g(const float* __restrict__ hin, const unsigned short* __restrict__ wbf,
            unsigned short* __restrict__ gws){
  __shared__ __align__(16) unsigned short uni[8192];    // h-tile [32][256] bf16
  const int t = threadIdx.x;
  const int lane = t & 63;
  const int w = t >> 6;
  const int b0 = blockIdx.x * 8;
  const int g = lane >> 4;
  const int ln = lane & 15;

  // ---- stage h tile (verified R4/R15)
  {
    const float* hb = hin + (size_t)b0 * 1024;
    #pragma unroll
    for (int it = 0; it < 4; ++it){
      int q = it * 256 + t;
      int row = q >> 5;
      int c = q & 31;
      const float* src = hb + row * 256 + c * 8;
      float4 f0 = *(const float4*)src;
      float4 f1 = *(const float4*)(src + 4);
      bf16x8 v;
      v[0]=(short)f2bf(f0.x); v[1]=(short)f2bf(f0.y); v[2]=(short)f2bf(f0.z); v[3]=(short)f2bf(f0.w);
      v[4]=(short)f2bf(f1.x); v[5]=(short)f2bf(f1.y); v[6]=(short)f2bf(f1.z); v[7]=(short)f2bf(f1.w);
      *(bf16x8*)&uni[row * 256 + ((c ^ (row & 7)) << 3)] = v;
    }
  }
  __syncthreads();

  f32x4 acc[2][8];
  #pragma unroll
  for (int m = 0; m < 2; ++m)
    #pragma unroll
    for (int c = 0; c < 8; ++c)
      acc[m][c] = (f32x4){0.f, 0.f, 0.f, 0.f};

  // ---- barrier-free K loop (verified R4/R15)
  for (int step = 0; step < 8; ++step){
    bf16x8 af[2], bfr[8];
    #pragma unroll
    for (int m = 0; m < 2; ++m){
      int row = m * 16 + ln;
      int chunk = step * 4 + g;
      af[m] = *(const bf16x8*)&uni[row * 256 + ((chunk ^ (row & 7)) << 3)];
    }
    const unsigned short* wp = wbf + (size_t)step * 16384 + (size_t)g * 4096
                             + (size_t)(w * 64 + ln) * 8;
    #pragma unroll
    for (int c = 0; c < 4; ++c){
      bfr[c]     = *(const bf16x8*)(wp + c * 128);
      bfr[c + 4] = *(const bf16x8*)(wp + 2048 + c * 128);
    }
    __builtin_amdgcn_s_setprio(1);
    #pragma unroll
    for (int m = 0; m < 2; ++m)
      #pragma unroll
      for (int c = 0; c < 8; ++c)
        acc[m][c] = __builtin_amdgcn_mfma_f32_16x16x32_bf16(af[m], bfr[c], acc[m][c], 0, 0, 0);
    __builtin_amdgcn_s_setprio(0);
  }

  // ---- store g (bf16, lane-natural, fully coalesced 8B/lane)
  #pragma unroll
  for (int m = 0; m < 2; ++m)
    #pragma unroll
    for (int c = 0; c < 8; ++c){
      ushort4 s;
      s.x = f2bf(acc[m][c][0]); s.y = f2bf(acc[m][c][1]);
      s.z = f2bf(acc[m][c][2]); s.w = f2bf(acc[m][c][3]);
      size_t idx16 = (((size_t)blockIdx.x * 4 + w) * 2 + m) * 8 + c;
      *(ushort4*)&gws[idx16 * 256 + lane * 4] = s;
    }
}

// ============ kernel B = verified R15 attention/LN, acc reloaded from ws ============
__global__ __launch_bounds__(256, 2)
void attn_g(const unsigned short* __restrict__ gws, const float* __restrict__ ebias,
            const float* __restrict__ avec, const float* __restrict__ gmw,
            const float* __restrict__ btw, float* __restrict__ out){
  __shared__ float red1[128], red2[128];
  __shared__ float eb_s[16];
  const int t = threadIdx.x;
  const int lane = t & 63;
  const int w = t >> 6;
  const int b0 = blockIdx.x * 8;
  const int g = lane >> 4;
  const int ln = lane & 15;

  float av[4];
  #pragma unroll
  for (int c = 0; c < 4; ++c) av[c] = avec[w * 64 + c * 16 + ln];
  if (t < 16) eb_s[t] = ebias[t];
  __syncthreads();

  #pragma unroll
  for (int m = 0; m < 2; ++m){
    // reload this m's acc (bf16-g attention numerics verified R1/R4/R6/R7 at 0.03125)
    f32x4 acc[8];
    #pragma unroll
    for (int c = 0; c < 8; ++c){
      size_t idx16 = (((size_t)blockIdx.x * 4 + w) * 2 + m) * 8 + c;
      ushort4 s = *(const ushort4*)&gws[idx16 * 256 + lane * 4];
      acc[c] = (f32x4){bf2f(s.x), bf2f(s.y), bf2f(s.z), bf2f(s.w)};
    }

    float e[16];
    #pragma unroll
    for (int q = 0; q < 16; ++q) e[q] = 0.f;
    #pragma unroll
    for (int c = 0; c < 4; ++c){
      f32x4 GL = acc[c];
      f32x4 GR = acc[c + 4];
      #pragma unroll
      for (int i = 0; i < 4; ++i)
        #pragma unroll
        for (int j = 0; j < 4; ++j){
          float x = GL[i] + GR[j];
          x = fmaxf(x, SLOPE * x);        // leaky_relu
          e[i * 4 + j] = fmaf(x, av[c], e[i * 4 + j]);
        }
    }
    #pragma unroll
    for (int mask = 1; mask <= 8; mask <<= 1)
      #pragma unroll
      for (int q = 0; q < 16; ++q)
        e[q] += __shfl_xor(e[q], mask);
    #pragma unroll
    for (int q = 0; q < 16; ++q) e[q] += eb_s[q];
    #pragma unroll
    for (int i = 0; i < 4; ++i){
      float mx = fmaxf(fmaxf(e[i*4+0], e[i*4+1]), fmaxf(e[i*4+2], e[i*4+3]));
      float p0 = __expf(e[i*4+0] - mx);
      float p1 = __expf(e[i*4+1] - mx);
      float p2 = __expf(e[i*4+2] - mx);
      float p3 = __expf(e[i*4+3] - mx);
      float rs = 1.f / (p0 + p1 + p2 + p3);
      e[i*4+0] = p0 * rs; e[i*4+1] = p1 * rs; e[i*4+2] = p2 * rs; e[i*4+3] = p3 * rs;
    }
    float hp[4][4];
    #pragma unroll
    for (int i = 0; i < 4; ++i){
      #pragma unroll
      for (int c = 0; c < 4; ++c){
        f32x4 GR = acc[c + 4];
        float v = e[i*4+0] * GR[0];
        v = fmaf(e[i*4+1], GR[1], v);
        v = fmaf(e[i*4+2], GR[2], v);
        v = fmaf(e[i*4+3], GR[3], v);
        hp[i][c] = v;
      }
      float s1 = hp[i][0] + hp[i][1] + hp[i][2] + hp[i][3];
      float s2 = fmaf(hp[i][0], hp[i][0],
                 fmaf(hp[i][1], hp[i][1],
                 fmaf(hp[i][2], hp[i][2], hp[i][3] * hp[i][3])));
      #pragma unroll
      for (int mask = 1; mask <= 8; mask <<= 1){
        s1 += __shfl_xor(s1, mask);
        s2 += __shfl_xor(s2, mask);
      }
      int r = (m * 4 + g) * 4 + i;        // disjoint per m
      if (ln == 0){ red1[r * 4 + w] = s1; red2[r * 4 + w] = s2; }
    }
    __syncthreads();

    float gmr[4], btr[4];
    #pragma unroll
    for (int c = 0; c < 4; ++c){
      gmr[c] = gmw[w * 64 + c * 16 + ln];
      btr[c] = btw[w * 64 + c * 16 + ln];
    }
    #pragma unroll
    for (int i = 0; i < 4; ++i){
      int r = (m * 4 + g) * 4 + i;
      float4 v1 = *(const float4*)&red1[r * 4];
      float4 v2 = *(const float4*)&red2[r * 4];
      float s1 = (v1.x + v1.y) + (v1.z + v1.w);
      float s2 = (v2.x + v2.y) + (v2.z + v2.w);
      float mu = s1 * (1.f / 256.f);
      float var = s2 * (1.f / 256.f) - mu * mu;
      float inv = rsqrtf(var + LN_EPS);
      float* op = out + ((size_t)b0 * 4 + r) * 256 + w * 64 + ln;
      #pragma unroll
      for (int c = 0; c < 4; ++c)
        op[c * 16] = fmaf((hp[i][c] - mu) * inv, gmr[c], btr[c]);
    }
  }
}

// ============ FUSED FALLBACK (R15 verbatim, 97 us verified) ============
template<bool USE_WS>
__global__ __launch_bounds__(256, 2)
void gat_fused(const float* __restrict__ hin, const float* __restrict__ ebias,
               const float* __restrict__ Wl, const float* __restrict__ Wr,
               const float* __restrict__ avec, const float* __restrict__ gmw,
               const float* __restrict__ btw, const unsigned short* __restrict__ wbf,
               float* __restrict__ out){
  __shared__ __align__(16) unsigned short uni[8192];
  __shared__ float red1[128], red2[128];
  __shared__ float eb_s[16];

  const int t = threadIdx.x;
  const int lane = t & 63;
  const int w = t >> 6;
  const int b0 = blockIdx.x * 8;
  const int g = lane >> 4;
  const int ln = lane & 15;

  float av[4];
  #pragma unroll
  for (int c = 0; c < 4; ++c) av[c] = avec[w * 64 + c * 16 + ln];
  if (t < 16) eb_s[t] = ebias[t];

  {
    const float* hb = hin + (size_t)b0 * 1024;
    #pragma unroll
    for (int it = 0; it < 4; ++it){
      int q = it * 256 + t;
      int row = q >> 5;
      int c = q & 31;
      const float* src = hb + row * 256 + c * 8;
      float4 f0 = *(const float4*)src;
      float4 f1 = *(const float4*)(src + 4);
      bf16x8 v;
      v[0]=(short)f2bf(f0.x); v[1]=(short)f2bf(f0.y); v[2]=(short)f2bf(f0.z); v[3]=(short)f2bf(f0.w);
      v[4]=(short)f2bf(f1.x); v[5]=(short)f2bf(f1.y); v[6]=(short)f2bf(f1.z); v[7]=(short)f2bf(f1.w);
      *(bf16x8*)&uni[row * 256 + ((c ^ (row & 7)) << 3)] = v;
    }
  }
  __syncthreads();

  f32x4 acc[2][8];
  #pragma unroll
  for (int m = 0; m < 2; ++m)
    #pragma unroll
    for (int c = 0; c < 8; ++c)
      acc[m][c] = (f32x4){0.f, 0.f, 0.f, 0.f};

  for (int step = 0; step < 8; ++step){
    bf16x8 af[2], bfr[8];
    #pragma unroll
    for (int m = 0; m < 2; ++m){
      int row = m * 16 + ln;
      int chunk = step * 4 + g;
      af[m] = *(const bf16x8*)&uni[row * 256 + ((chunk ^ (row & 7)) << 3)];
    }
    if constexpr (USE_WS){
      const unsigned short* wp = wbf + (size_t)step * 16384 + (size_t)g * 4096
                               + (size_t)(w * 64 + ln) * 8;
      #pragma unroll
      for (int c = 0; c < 4; ++c){
        bfr[c]     = *(const bf16x8*)(wp + c * 128);
        bfr[c + 4] = *(const bf16x8*)(wp + 2048 + c * 128);
      }
    } else {
      #pragma unroll
      for (int c = 0; c < 4; ++c){
        int col = w * 64 + c * 16 + ln;
        #pragma unroll
        for (int j = 0; j < 8; ++j){
          bfr[c][j]     = (short)f2bf(Wl[(step * 32 + g * 8 + j) * 256 + col]);
          bfr[c + 4][j] = (short)f2bf(Wr[(step * 32 + g * 8 + j) * 256 + col]);
        }
      }
    }
    __builtin_amdgcn_s_setprio(1);
    #pragma unroll
    for (int m = 0; m < 2; ++m)
      #pragma unroll
      for (int c = 0; c < 8; ++c)
        acc[m][c] = __builtin_amdgcn_mfma_f32_16x16x32_bf16(af[m], bfr[c], acc[m][c], 0, 0, 0);
    __builtin_amdgcn_s_setprio(0);
  }

  #pragma unroll
  for (int m = 0; m < 2; ++m){
    float e[16];
    #pragma unroll
    for (int q = 0; q < 16; ++q) e[q] = 0.f;
    #pragma unroll
    for (int c = 0; c < 4; ++c){
      f32x4 GL = acc[m][c];
      f32x4 GR = acc[m][c + 4];
      #pragma unroll
      for (int i = 0; i < 4; ++i)
        #pragma unroll
        for (int j = 0; j < 4; ++j){
          float x = GL[i] + GR[j];
          x = fmaxf(x, SLOPE * x);
          e[i * 4 + j] = fmaf(x, av[c], e[i * 4 + j]);
        }
    }
    #pragma unroll
    for (int mask = 1; mask <= 8; mask <<= 1)
      #pragma unroll
      for (int q = 0; q < 16; ++q)
        e[q] += __shfl_xor(e[q], mask);
    #pragma unroll
    for (int q = 0; q < 16; ++q) e[q] += eb_s[q];
    #pragma unroll
    for (int i = 0; i < 4; ++i){
      float mx = fmaxf(fmaxf(e[i*4+0], e[i*4+1]), fmaxf(e[i*4+2], e[i*4+3]));
      float p0 = __expf(e[i*4+0] - mx);
      float p1 = __expf(e[i*4+1] - mx);
      float p2 = __expf(e[i*4+2] - mx);
      float p3 = __expf(e[i*4+3] - mx);
      float rs = 1.f / (p0 + p1 + p2 + p3);
      e[i*4+0] = p0 * rs; e[i*4+1] = p1 * rs; e[i*4+2] = p2 * rs; e[i*4+3] = p3 * rs;
    }
    float hp[4][4];
    #pragma unroll
    for (int i = 0; i < 4; ++i){
      #pragma unroll
      for (int c = 0; c < 4; ++c){
        f32x4 GR = acc[m][c + 4];
        float v = e[i*4+0] * GR[0];
        v = fmaf(e[i*4+1], GR[1], v);
        v = fmaf(e[i*4+2], GR[2], v);
        v = fmaf(e[i*4+3], GR[3], v);
        hp[i][c] = v;
      }
      float s1 = hp[i][0] + hp[i][1] + hp[i][2] + hp[i][3];
      float s2 = fmaf(hp[i][0], hp[i][0],
                 fmaf(hp[i][1], hp[i][1],
                 fmaf(hp[i][2], hp[i][2], hp[i][3] * hp[i][3])));
      #pragma unroll
      for (int mask = 1; mask <= 8; mask <<= 1){
        s1 += __shfl_xor(s1, mask);
        s2 += __shfl_xor(s2, mask);
      }
      int r = (m * 4 + g) * 4 + i;
      if (ln == 0){ red1[r * 4 + w] = s1; red2[r * 4 + w] = s2; }
    }
    __syncthreads();

    float gmr[4], btr[4];
    #pragma unroll
    for (int c = 0; c < 4; ++c){
      gmr[c] = gmw[w * 64 + c * 16 + ln];
      btr[c] = btw[w * 64 + c * 16 + ln];
    }
    #pragma unroll
    for (int i = 0; i < 4; ++i){
      int r = (m * 4 + g) * 4 + i;
      float4 v1 = *(const float4*)&red1[r * 4];
      float4 v2 = *(const float4*)&red2[r * 4];
      float s1 = (v1.x + v1.y) + (v1.z + v1.w);
      float s2 = (v2.x + v2.y) + (v2.z + v2.w);
      float mu = s1 * (1.f / 256.f);
      float var = s2 * (1.f / 256.f) - mu * mu;
      float inv = rsqrtf(var + LN_EPS);
      float* op = out + ((size_t)b0 * 4 + r) * 256 + w * 64 + ln;
      #pragma unroll
      for (int c = 0; c < 4; ++c)
        op[c * 16] = fmaf((hp[i][c] - mu) * inv, gmr[c], btr[c]);
    }
  }
}

extern "C" void kernel_launch(void* const* d_in, const int* in_sizes, int n_in,
                              void* d_out, int out_size, void* d_ws, size_t ws_size,
                              hipStream_t stream){
  const float* h  = (const float*)d_in[0];
  const float* eb = (const float*)d_in[1];
  const float* Wl = (const float*)d_in[2];
  const float* Wr = (const float*)d_in[3];
  const float* a  = (const float*)d_in[4];
  const float* gm = (const float*)d_in[5];
  const float* bt = (const float*)d_in[6];
  float* out = (float*)d_out;
  (void)n_in; (void)out_size;

  int B = in_sizes[0] / 1024;        // (B, 4, 256) f32
  int nblk = B / 8;
  size_t gbytes = (size_t)B * 4 * 512 * 2;   // g tile, bf16

  if (ws_size >= 262144 + gbytes){
    unsigned short* wbf = (unsigned short*)d_ws;
    unsigned short* gws = wbf + 131072;
    wconv_kernel<<<64, 256, 0, stream>>>(Wl, Wr, wbf);
    gemm_g<<<nblk, 256, 0, stream>>>(h, wbf, gws);
    attn_g<<<nblk, 256, 0, stream>>>(gws, eb, a, gm, bt, out);
  } else if (ws_size >= 262144){
    unsigned short* wbf = (unsigned short*)d_ws;
    wconv_kernel<<<64, 256, 0, stream>>>(Wl, Wr, wbf);
    gat_fused<true><<<nblk, 256, 0, stream>>>(h, eb, Wl, Wr, a, gm, bt, wbf, out);
  } else {
    gat_fused<false><<<nblk, 256, 0, stream>>>(h, eb, Wl, Wr, a, gm, bt, nullptr, out);
  }
}

// Round 17
// 95.618 us; speedup vs baseline: 1.4881x; 1.4881x over previous
//
#include <hip/hip_runtime.h>
#include <hip/hip_bf16.h>

typedef short bf16x8 __attribute__((ext_vector_type(8)));
typedef float f32x4 __attribute__((ext_vector_type(4)));

#define LN_EPS 1e-5f
#define SLOPE 0.2f

// Native conversion: compiler fuses adjacent pairs to v_cvt_pk_bf16_f32 (m240).
__device__ __forceinline__ unsigned short f2bf(float f){
  __hip_bfloat16 b = __float2bfloat16(f);
  return *reinterpret_cast<unsigned short*>(&b);
}

// Verified W image (rounds 1..15):
// wbf[((s*4+g)*512 + c)*8 + j] = W[k = s*32+g*8+j][c]   (c<256: W_l, else W_r)
__global__ void wconv_kernel(const float* __restrict__ Wl,
                             const float* __restrict__ Wr,
                             unsigned short* __restrict__ wbf){
  int idx = blockIdx.x * 256 + threadIdx.x;   // 0..16383 : (s,g,c)
  int c = idx & 511;
  int gg = (idx >> 9) & 3;
  int s = idx >> 11;
  int k0 = s * 32 + gg * 8;
  const float* src = (c < 256) ? (Wl + c) : (Wr + (c - 256));
  bf16x8 v;
  #pragma unroll
  for (int j = 0; j < 8; ++j) v[j] = (short)f2bf(src[(k0 + j) * 256]);
  *(bf16x8*)&wbf[(size_t)idx * 8] = v;
}

// R15 fused structure (best verified: 97 us) with the k-loop SOFTWARE-PIPELINED:
// R16's split isolated the GEMM phase at 99 us with MfmaUtil 13% / VALU 7.5% —
// a pure latency chain (rolled loop: loads -> wait -> MFMA). Here each half-step's
// MFMA cluster covers the other half's in-flight loads; af prefetched from LDS
// one step ahead. Same fragment addresses/pairing as R15 — reorder only.
// NOTE: minwaves/EU >= 4 in __launch_bounds__ MISCOMPILES (R5->R6 test). Keep 2.
template<bool USE_WS>
__global__ __launch_bounds__(256, 2)
void gat_fused(const float* __restrict__ hin, const float* __restrict__ ebias,
               const float* __restrict__ Wl, const float* __restrict__ Wr,
               const float* __restrict__ avec, const float* __restrict__ gmw,
               const float* __restrict__ btw, const unsigned short* __restrict__ wbf,
               float* __restrict__ out){
  __shared__ __align__(16) unsigned short uni[8192];    // h-tile [32][256] bf16, 16KB
  __shared__ float red1[128], red2[128];                // [row][wave] LN partials
  __shared__ float eb_s[16];

  const int t = threadIdx.x;
  const int lane = t & 63;
  const int w = t >> 6;
  const int b0 = blockIdx.x * 8;
  const int g = lane >> 4;
  const int ln = lane & 15;

  float av[4];
  #pragma unroll
  for (int c = 0; c < 4; ++c) av[c] = avec[w * 64 + c * 16 + ln];
  if (t < 16) eb_s[t] = ebias[t];

  // ---- stage h tile (32 rows x 256 k) f32->bf16, XOR-swizzled (verified R4)
  {
    const float* hb = hin + (size_t)b0 * 1024;
    #pragma unroll
    for (int it = 0; it < 4; ++it){
      int q = it * 256 + t;              // 16B-chunk id, 1024 total
      int row = q >> 5;
      int c = q & 31;
      const float* src = hb + row * 256 + c * 8;
      float4 f0 = *(const float4*)src;
      float4 f1 = *(const float4*)(src + 4);
      bf16x8 v;
      v[0]=(short)f2bf(f0.x); v[1]=(short)f2bf(f0.y); v[2]=(short)f2bf(f0.z); v[3]=(short)f2bf(f0.w);
      v[4]=(short)f2bf(f1.x); v[5]=(short)f2bf(f1.y); v[6]=(short)f2bf(f1.z); v[7]=(short)f2bf(f1.w);
      *(bf16x8*)&uni[row * 256 + ((c ^ (row & 7)) << 3)] = v;
    }
  }
  __syncthreads();

  f32x4 acc[2][8];
  #pragma unroll
  for (int m = 0; m < 2; ++m)
    #pragma unroll
    for (int c = 0; c < 8; ++c)
      acc[m][c] = (f32x4){0.f, 0.f, 0.f, 0.f};

  // ---- pipelined K loop (values identical to R15; issue order changed)
  if constexpr (USE_WS){
    const unsigned short* wbase = wbf + (size_t)g * 4096 + (size_t)(w * 64 + ln) * 8;
    bf16x8 af[2], afn[2], P[4], Q[4];
    #pragma unroll
    for (int m = 0; m < 2; ++m)
      af[m] = *(const bf16x8*)&uni[(m * 16 + ln) * 256 + ((g ^ (ln & 7)) << 3)];
    #pragma unroll
    for (int c = 0; c < 4; ++c)
      P[c] = *(const bf16x8*)(wbase + c * 128);          // gl(0)

    #pragma unroll
    for (int step = 0; step < 8; ++step){
      const unsigned short* wp = wbase + (size_t)step * 16384;
      #pragma unroll
      for (int c = 0; c < 4; ++c)
        Q[c] = *(const bf16x8*)(wp + 2048 + c * 128);    // gr(step)
      if (step < 7){
        #pragma unroll
        for (int m = 0; m < 2; ++m)
          afn[m] = *(const bf16x8*)&uni[(m * 16 + ln) * 256
                     + ((((step + 1) * 4 + g) ^ (ln & 7)) << 3)];
      }
      __builtin_amdgcn_s_setprio(1);
      #pragma unroll
      for (int m = 0; m < 2; ++m)
        #pragma unroll
        for (int c = 0; c < 4; ++c)
          acc[m][c] = __builtin_amdgcn_mfma_f32_16x16x32_bf16(af[m], P[c], acc[m][c], 0, 0, 0);
      __builtin_amdgcn_s_setprio(0);
      if (step < 7){
        const unsigned short* wpn = wp + 16384;
        #pragma unroll
        for (int c = 0; c < 4; ++c)
          P[c] = *(const bf16x8*)(wpn + c * 128);        // gl(step+1)
      }
      __builtin_amdgcn_s_setprio(1);
      #pragma unroll
      for (int m = 0; m < 2; ++m)
        #pragma unroll
        for (int c = 0; c < 4; ++c)
          acc[m][c + 4] = __builtin_amdgcn_mfma_f32_16x16x32_bf16(af[m], Q[c], acc[m][c + 4], 0, 0, 0);
      __builtin_amdgcn_s_setprio(0);
      af[0] = afn[0]; af[1] = afn[1];
    }
  } else {
    for (int step = 0; step < 8; ++step){
      bf16x8 af[2], bfr[8];
      #pragma unroll
      for (int m = 0; m < 2; ++m){
        int row = m * 16 + ln;
        int chunk = step * 4 + g;
        af[m] = *(const bf16x8*)&uni[row * 256 + ((chunk ^ (row & 7)) << 3)];
      }
      #pragma unroll
      for (int c = 0; c < 4; ++c){
        int col = w * 64 + c * 16 + ln;
        #pragma unroll
        for (int j = 0; j < 8; ++j){
          bfr[c][j]     = (short)f2bf(Wl[(step * 32 + g * 8 + j) * 256 + col]);
          bfr[c + 4][j] = (short)f2bf(Wr[(step * 32 + g * 8 + j) * 256 + col]);
        }
      }
      #pragma unroll
      for (int m = 0; m < 2; ++m)
        #pragma unroll
        for (int c = 0; c < 8; ++c)
          acc[m][c] = __builtin_amdgcn_mfma_f32_16x16x32_bf16(af[m], bfr[c], acc[m][c], 0, 0, 0);
    }
  }

  // ---- attention + per-m epilogue (R13/R15 verbatim algebra)
  #pragma unroll
  for (int m = 0; m < 2; ++m){
    float e[16];
    #pragma unroll
    for (int q = 0; q < 16; ++q) e[q] = 0.f;
    #pragma unroll
    for (int c = 0; c < 4; ++c){
      f32x4 GL = acc[m][c];
      f32x4 GR = acc[m][c + 4];
      #pragma unroll
      for (int i = 0; i < 4; ++i)
        #pragma unroll
        for (int j = 0; j < 4; ++j){
          float x = GL[i] + GR[j];
          x = fmaxf(x, SLOPE * x);        // leaky_relu
          e[i * 4 + j] = fmaf(x, av[c], e[i * 4 + j]);
        }
    }
    #pragma unroll
    for (int mask = 1; mask <= 8; mask <<= 1)
      #pragma unroll
      for (int q = 0; q < 16; ++q)
        e[q] += __shfl_xor(e[q], mask);
    #pragma unroll
    for (int q = 0; q < 16; ++q) e[q] += eb_s[q];
    #pragma unroll
    for (int i = 0; i < 4; ++i){
      float mx = fmaxf(fmaxf(e[i*4+0], e[i*4+1]), fmaxf(e[i*4+2], e[i*4+3]));
      float p0 = __expf(e[i*4+0] - mx);
      float p1 = __expf(e[i*4+1] - mx);
      float p2 = __expf(e[i*4+2] - mx);
      float p3 = __expf(e[i*4+3] - mx);
      float rs = 1.f / (p0 + p1 + p2 + p3);
      e[i*4+0] = p0 * rs; e[i*4+1] = p1 * rs; e[i*4+2] = p2 * rs; e[i*4+3] = p3 * rs;
    }
    float hp[4][4];
    #pragma unroll
    for (int i = 0; i < 4; ++i){
      #pragma unroll
      for (int c = 0; c < 4; ++c){
        f32x4 GR = acc[m][c + 4];
        float v = e[i*4+0] * GR[0];
        v = fmaf(e[i*4+1], GR[1], v);
        v = fmaf(e[i*4+2], GR[2], v);
        v = fmaf(e[i*4+3], GR[3], v);
        hp[i][c] = v;
      }
      float s1 = hp[i][0] + hp[i][1] + hp[i][2] + hp[i][3];
      float s2 = fmaf(hp[i][0], hp[i][0],
                 fmaf(hp[i][1], hp[i][1],
                 fmaf(hp[i][2], hp[i][2], hp[i][3] * hp[i][3])));
      #pragma unroll
      for (int mask = 1; mask <= 8; mask <<= 1){
        s1 += __shfl_xor(s1, mask);
        s2 += __shfl_xor(s2, mask);
      }
      int r = (m * 4 + g) * 4 + i;        // disjoint ranges per m
      if (ln == 0){ red1[r * 4 + w] = s1; red2[r * 4 + w] = s2; }
    }
    __syncthreads();

    float gmr[4], btr[4];
    #pragma unroll
    for (int c = 0; c < 4; ++c){
      gmr[c] = gmw[w * 64 + c * 16 + ln];
      btr[c] = btw[w * 64 + c * 16 + ln];
    }
    #pragma unroll
    for (int i = 0; i < 4; ++i){
      int r = (m * 4 + g) * 4 + i;
      float4 v1 = *(const float4*)&red1[r * 4];
      float4 v2 = *(const float4*)&red2[r * 4];
      float s1 = (v1.x + v1.y) + (v1.z + v1.w);
      float s2 = (v2.x + v2.y) + (v2.z + v2.w);
      float mu = s1 * (1.f / 256.f);
      float var = s2 * (1.f / 256.f) - mu * mu;
      float inv = rsqrtf(var + LN_EPS);
      float* op = out + ((size_t)b0 * 4 + r) * 256 + w * 64 + ln;
      #pragma unroll
      for (int c = 0; c < 4; ++c)
        op[c * 16] = fmaf((hp[i][c] - mu) * inv, gmr[c], btr[c]);
    }
  }
}

extern "C" void kernel_launch(void* const* d_in, const int* in_sizes, int n_in,
                              void* d_out, int out_size, void* d_ws, size_t ws_size,
                              hipStream_t stream){
  const float* h  = (const float*)d_in[0];
  const float* eb = (const float*)d_in[1];
  const float* Wl = (const float*)d_in[2];
  const float* Wr = (const float*)d_in[3];
  const float* a  = (const float*)d_in[4];
  const float* gm = (const float*)d_in[5];
  const float* bt = (const float*)d_in[6];
  float* out = (float*)d_out;
  (void)n_in; (void)out_size;

  int B = in_sizes[0] / 1024;        // (B, 4, 256) f32
  int nblk = B / 8;

  if (ws_size >= 262144){
    unsigned short* wbf = (unsigned short*)d_ws;
    wconv_kernel<<<64, 256, 0, stream>>>(Wl, Wr, wbf);
    gat_fused<true><<<nblk, 256, 0, stream>>>(h, eb, Wl, Wr, a, gm, bt, wbf, out);
  } else {
    gat_fused<false><<<nblk, 256, 0, stream>>>(h, eb, Wl, Wr, a, gm, bt, nullptr, out);
  }
}